// Round 5
// baseline (611.846 us; speedup 1.0000x reference)
//
#include <hip/hip_runtime.h>
#include <cstdint>
#include <cstddef>

// Problem constants (fixed by reference)
#define BATCH 32
#define SEQ   2048
#define DIM   1024      // ENC_D = DEC_D = ATTN_D = OUT_D = 1024
#define MROWS (BATCH*SEQ)   // 65536

typedef __attribute__((ext_vector_type(4))) float  floatx4;
typedef __attribute__((ext_vector_type(8))) short  short8;

// fp32 -> bf16 round-to-nearest-even
__device__ __forceinline__ unsigned short f2bf(float f) {
  unsigned int u = __float_as_uint(f);
  u += 0x7fffu + ((u >> 16) & 1u);
  return (unsigned short)(u >> 16);
}

// async global->LDS, 16B per lane; LDS dest = wave-uniform base + lane*16
__device__ __forceinline__ void async16(const void* g, void* l) {
  __builtin_amdgcn_global_load_lds(
      (const __attribute__((address_space(1))) unsigned int*)g,
      (__attribute__((address_space(3))) unsigned int*)l, 16, 0, 0);
}

__device__ __forceinline__ float fast_tanh(float x) {
  float e = __expf(2.0f * x);
  return 1.0f - 2.0f * __builtin_amdgcn_rcpf(1.0f + e);
}

// ---------------------------------------------------------------------------
// Kernel 0: Abf[b][s][k] = bf16(enc_states[b][s][k]); rows >= len skipped
// ---------------------------------------------------------------------------
__global__ void k_convert(const float* __restrict__ enc, const int* __restrict__ enc_len,
                          unsigned short* __restrict__ Abf) {
  int b = blockIdx.y;
  int r0 = blockIdx.x * 8;                 // 8 rows per block
  if (r0 >= enc_len[b]) return;
  size_t base = ((size_t)b * SEQ + r0) * DIM;
  const float4* src = (const float4*)(enc + base);
  ushort4* dst = (ushort4*)(Abf + base);
  int tid = threadIdx.x;
#pragma unroll
  for (int i = 0; i < 8; ++i) {
    float4 v = src[tid + i * 256];
    ushort4 h;
    h.x = f2bf(v.x); h.y = f2bf(v.y); h.z = f2bf(v.z); h.w = f2bf(v.w);
    dst[tid + i * 256] = h;
  }
}

// ---------------------------------------------------------------------------
// Kernel 1: Wt[n][k] = bf16(W_enc[k][n])  (1024x1024)
// ---------------------------------------------------------------------------
__global__ void k_transpose(const float* __restrict__ W, unsigned short* __restrict__ Wt) {
  __shared__ float tile[32][33];
  int n0 = blockIdx.x * 32, k0 = blockIdx.y * 32;
  int tx = threadIdx.x, ty = threadIdx.y;   // (32, 8)
#pragma unroll
  for (int i = 0; i < 4; ++i) {
    int y = ty + i * 8;
    tile[y][tx] = W[(size_t)(k0 + y) * DIM + n0 + tx];
  }
  __syncthreads();
#pragma unroll
  for (int i = 0; i < 4; ++i) {
    int y = ty + i * 8;
    Wt[(size_t)(n0 + y) * DIM + k0 + tx] = f2bf(tile[tx][y]);
  }
}

// ---------------------------------------------------------------------------
// Kernel 2: dech[b][a] += dec_states[b, z-chunk] @ W_dec[z-chunk, a]
// R5: 8 batches per block (grid 4 x 4 x 8) so W_dec is read 4x, not 32x
// (was 128 MB of redundant weight traffic). dec loads are wave-uniform
// (scalar path). chunk z==0 adds biases; dech pre-zeroed.
// ---------------------------------------------------------------------------
__global__ void k_dech(const float* __restrict__ dec, const float* __restrict__ W_dec,
                       const float* __restrict__ b_dec, const float* __restrict__ b_enc,
                       float* __restrict__ dech) {
  int a  = blockIdx.x * 256 + threadIdx.x;
  int bg = blockIdx.y * 8;
  int z  = blockIdx.z;
  float bias = (z == 0) ? (b_dec[a] + b_enc[a]) : 0.0f;
  float acc[8];
#pragma unroll
  for (int j = 0; j < 8; ++j) acc[j] = bias;
  const float* wc = W_dec + (size_t)z * 128 * DIM + a;
#pragma unroll 4
  for (int e = 0; e < 128; ++e) {
    float w = wc[(size_t)e * DIM];
#pragma unroll
    for (int j = 0; j < 8; ++j)
      acc[j] = fmaf(dec[(size_t)(bg + j) * DIM + z * 128 + e], w, acc[j]);
  }
#pragma unroll
  for (int j = 0; j < 8; ++j)
    atomicAdd(&dech[(size_t)(bg + j) * DIM + a], acc[j]);
}

// ---------------------------------------------------------------------------
// Kernel 3: 256x256-tile 8-phase GEMM + tanh-dot epilogue.
//   score[m] += sum_n tanh( (Abf@Wt^T)[m][n] + dech[b(m)][n] ) * w_attn[n]
// BM=BN=256, BK=64, 512 thr = 8 waves (2M x 4N), per-wave 128x64 out.
// LDS 128 KB: A bufs @ 0/32K, B bufs @ 64K/96K; 128 B per row (64 bf16).
// Swizzle: physical = logical ^ (((logical>>7)&7)<<4) (16B-granular involution);
// read side XORs the k-slot byte; stage side pre-swizzles the per-lane GLOBAL
// source; LDS dest stays linear (rule 21).
//
// R5 SCHEDULE (balance + read-ahead, m201-conformant {8,4,8,4}):
//   4 reg slots of 4 b128 each (64 VGPR): SP_ (A f01 on entry), aX, bX, SQ_.
//   ph1: rd A-f23->aX, B0->bX        ; MFMA Q(0,0) = [SP_,aX] x bX
//   ph2: rd B1->SQ_                  ; MFMA Q(0,1) = [SP_,aX] x SQ_
//   ph3: stage B(t+2); rd f45->SP_, f67->aX ; MFMA Q(1,1) = [SP_,aX] x SQ_
//   ph4: stage A(t+2); VMCNT(8); rd A(t+1)f01 -> SQ_ (from buf^1, retired)
//                                    ; MFMA Q(1,0) = [SP_,aX] x bX
//   Slot roles SP_/SQ_ swap each tile (loop 2-unrolled for buffer parity).
//   The ph4 read is consumed by NEXT ph1 -> drains under Q(1,0) (overlap).
// Waits: at t.ph4, outstanding = {B(t+1),A(t+1),B(t+2),A(t+2)} = 16;
//   VMCNT(8) retires exactly B(t+1),A(t+1) (FIFO), keeps L(t+2) in flight.
//   Tail: tile14 (MODE1) no staging, VMCNT(0) then read A(15); tile15
//   (MODE2) no staging/waits/next-read.
// Overwrite hazards: region's last reads drain (lgkm before that phase's
//   MFMA) >=1 barrier before its staging phase -- checked per region.
// ---------------------------------------------------------------------------
#define PH_BAR do { asm volatile("" ::: "memory"); __builtin_amdgcn_s_barrier(); asm volatile("" ::: "memory"); } while(0)
#define SCHED0 __builtin_amdgcn_sched_barrier(0)
#define SP1 __builtin_amdgcn_s_setprio(1)
#define SP0 __builtin_amdgcn_s_setprio(0)
#define VMCNT(n) asm volatile("s_waitcnt vmcnt(" #n ")" ::: "memory")

__global__ void __launch_bounds__(512, 2) k_gemm256(
    const unsigned short* __restrict__ Abf, // [65536,1024] bf16
    const unsigned short* __restrict__ Wt,  // [1024 n][1024 k] bf16
    const float* __restrict__ dech,         // [32,1024]
    const float* __restrict__ w_attn,       // [1024]
    const int* __restrict__ enc_len,        // [32]
    float* __restrict__ score)              // [65536], pre-zeroed
{
  int bid = blockIdx.x;                 // 1024 blocks
  int t  = (bid & 7) * 128 + (bid >> 3); // bijective XCD swizzle (1024%8==0)
  int nb = t & 3;                        // col tile 0..3   (n0 = nb*256)
  int rt = t >> 2;                       // row tile 0..255 (m0 = rt*256)
  int bb = rt >> 3;                      // batch (8 row-tiles per batch)
  int len = enc_len[bb];
  if (((rt & 7) * 256) >= len) return;   // fully masked tile

  __shared__ __align__(16) char lds[131072];

  int tid = threadIdx.x;
  int w = tid >> 6, lane = tid & 63;
  int wr = w >> 2;               // 0..1  M-warp
  int wc = w & 3;                // 0..3  N-warp
  int li = lane & 15, g = lane >> 4;
  int xl = (li & 7) << 4;        // lane-constant read swizzle

  const char* Ag = (const char*)(Abf + (size_t)rt * 256 * DIM);
  const char* Bg = (const char*)(Wt  + (size_t)nb * 256 * DIM);

  // pre-swizzled stage source offsets, collapsed to linear form:
  //   soff(h,i) = (h*128 + (w*2+i)*8 + (lane>>3))*2048
  //               + (((lane&7)<<4) ^ (((lane>>3)&7)<<4))
  // (algebraically identical to the R3/R4 per-element XOR computation)
  size_t sbase = (size_t)((lane >> 3) * 2048 +
                 (((lane & 7) << 4) ^ (((lane >> 3) & 7) << 4)));
  size_t swoff = (size_t)(w * 2) * 16384;   // i adds 16384; h adds 262144
  int    ldbase = w * 2048;                 // wave-uniform LDS dest (i adds 1024, h adds 16384)

#define STAGE_A(buf, h, kt) do { \
  async16(Ag + sbase + swoff + (size_t)(h) * 262144 + (size_t)(kt) * 128, \
          lds + (buf) * 32768 + ldbase + (h) * 16384); \
  async16(Ag + sbase + swoff + 16384 + (size_t)(h) * 262144 + (size_t)(kt) * 128, \
          lds + (buf) * 32768 + ldbase + 1024 + (h) * 16384); \
} while (0)
#define STAGE_B(buf, h, kt) do { \
  async16(Bg + sbase + swoff + (size_t)(h) * 262144 + (size_t)(kt) * 128, \
          lds + 65536 + (buf) * 32768 + ldbase + (h) * 16384); \
  async16(Bg + sbase + swoff + 16384 + (size_t)(h) * 262144 + (size_t)(kt) * 128, \
          lds + 65536 + (buf) * 32768 + ldbase + 1024 + (h) * 16384); \
} while (0)

  short8 sA0[2][2], sA1[2][2];   // rotating A f01 / B1 slots
  short8 aX[2][2];               // A high frag-pair of current half
  short8 bX[2][2];               // B0
  floatx4 acc[8][4] = {};        // 8 m-frags x 4 n-frags

// read A frag-pair (f0, f0+1), each 2 ksub
#define RD_A2(buf, f0, DST) do { \
  const char* base_ = lds + (buf) * 32768 + (wr * 128 + (f0) * 16 + li) * 128; \
  int c0_ = (g * 16) ^ xl; \
  _Pragma("unroll") for (int j = 0; j < 2; ++j) { \
    DST[j][0] = *(const short8*)(base_ + j * 2048 + c0_); \
    DST[j][1] = *(const short8*)(base_ + j * 2048 + (c0_ ^ 64)); \
  } \
} while (0)
#define RD_B(buf, nh, DST) do { \
  const char* base_ = lds + 65536 + (buf) * 32768 + (wc * 64 + (nh) * 32 + li) * 128; \
  int c0_ = (g * 16) ^ xl; \
  _Pragma("unroll") for (int tnq = 0; tnq < 2; ++tnq) { \
    DST[tnq][0] = *(const short8*)(base_ + tnq * 2048 + c0_); \
    DST[tnq][1] = *(const short8*)(base_ + tnq * 2048 + (c0_ ^ 64)); \
  } \
} while (0)
// one C-quadrant: A = [ALO(frags mh*4+0,1), AHI(frags mh*4+2,3)] x BB
#define MFMA_Q(mh, nh, ALO, AHI, BB) do { \
  _Pragma("unroll") for (int ks = 0; ks < 2; ++ks) \
  _Pragma("unroll") for (int tnq = 0; tnq < 2; ++tnq) { \
    acc[(mh)*4+0][(nh)*2+tnq] = __builtin_amdgcn_mfma_f32_16x16x32_bf16(ALO[0][ks], BB[tnq][ks], acc[(mh)*4+0][(nh)*2+tnq], 0, 0, 0); \
    acc[(mh)*4+1][(nh)*2+tnq] = __builtin_amdgcn_mfma_f32_16x16x32_bf16(ALO[1][ks], BB[tnq][ks], acc[(mh)*4+1][(nh)*2+tnq], 0, 0, 0); \
    acc[(mh)*4+2][(nh)*2+tnq] = __builtin_amdgcn_mfma_f32_16x16x32_bf16(AHI[0][ks], BB[tnq][ks], acc[(mh)*4+2][(nh)*2+tnq], 0, 0, 0); \
    acc[(mh)*4+3][(nh)*2+tnq] = __builtin_amdgcn_mfma_f32_16x16x32_bf16(AHI[1][ks], BB[tnq][ks], acc[(mh)*4+3][(nh)*2+tnq], 0, 0, 0); \
  } \
} while (0)

// MODE 0: steady. MODE 1: tile NT-2 (no staging, VMCNT(0) before next read).
// MODE 2: last tile (no staging, no waits, no next read).
#define TILE_STEP(CUR, KT2, MODE, SP_, SQ_) do { \
  /* ph1: Q(0,0) -- SP_ holds A f01 (read last ph4) */ \
  RD_A2(CUR, 2, aX); \
  RD_B(CUR, 0, bX); \
  PH_BAR; SCHED0; SP1; MFMA_Q(0, 0, SP_, aX, bX); SP0; SCHED0; \
  PH_BAR; \
  /* ph2: Q(0,1) -- last reads of CUR.B region */ \
  RD_B(CUR, 1, SQ_); \
  PH_BAR; SCHED0; SP1; MFMA_Q(0, 1, SP_, aX, SQ_); SP0; SCHED0; \
  PH_BAR; \
  /* ph3: Q(1,1) -- CUR.B dead: stage B(t+2); f01/f23 regs dead: reuse */ \
  if ((MODE) == 0) { STAGE_B(CUR, 0, KT2); STAGE_B(CUR, 1, KT2); } \
  RD_A2(CUR, 4, SP_); \
  RD_A2(CUR, 6, aX); \
  PH_BAR; SCHED0; SP1; MFMA_Q(1, 1, SP_, aX, SQ_); SP0; SCHED0; \
  PH_BAR; \
  /* ph4: Q(1,0) -- CUR.A dead: stage A(t+2); read-ahead A(t+1) f01 */ \
  if ((MODE) == 0) { STAGE_A(CUR, 0, KT2); STAGE_A(CUR, 1, KT2); } \
  if ((MODE) == 0) { VMCNT(8); } else if ((MODE) == 1) { VMCNT(0); } \
  if ((MODE) < 2) RD_A2((CUR) ^ 1, 0, SQ_); \
  PH_BAR; SCHED0; SP1; MFMA_Q(1, 0, SP_, aX, bX); SP0; SCHED0; \
  PH_BAR; \
} while (0)

  // prologue: L(0)->buf0, L(1)->buf1 (B then A per tile, matching steady
  // FIFO order); VMCNT(8) retires L(0), leaves L(1) in flight.
  STAGE_B(0, 0, 0); STAGE_B(0, 1, 0); STAGE_A(0, 0, 0); STAGE_A(0, 1, 0);
  STAGE_B(1, 0, 1); STAGE_B(1, 1, 1); STAGE_A(1, 0, 1); STAGE_A(1, 1, 1);
  VMCNT(8);
  PH_BAR;
  RD_A2(0, 0, sA0);   // tile0 f01 (drains under ph1's barrier)

  // main: tiles 0..13 stage tiles 2..15 (NT=16); slot roles swap per tile
#pragma unroll 1
  for (int u = 0; u < 14; u += 2) {
    TILE_STEP(0, u + 2, 0, sA0, sA1);
    TILE_STEP(1, u + 3, 0, sA1, sA0);
  }
  TILE_STEP(0, 0, 1, sA0, sA1);   // tile 14
  TILE_STEP(1, 0, 2, sA1, sA0);   // tile 15

  // epilogue: C/D layout col=lane&15 (n), row=(lane>>4)*4+reg (m)  [m89]
  float dh[4], wa[4];
#pragma unroll
  for (int tn = 0; tn < 4; ++tn) {
    int n = nb * 256 + wc * 64 + tn * 16 + li;
    dh[tn] = dech[(size_t)bb * DIM + n];
    wa[tn] = w_attn[n];
  }
#pragma unroll
  for (int tm = 0; tm < 8; ++tm) {
    int mrow = rt * 256 + wr * 128 + tm * 16 + g * 4;
#pragma unroll
    for (int r = 0; r < 4; ++r) {
      float v = 0.0f;
#pragma unroll
      for (int tn = 0; tn < 4; ++tn)
        v = fmaf(wa[tn], fast_tanh(acc[tm][tn][r] + dh[tn]), v);
      v += __shfl_xor(v, 1);
      v += __shfl_xor(v, 2);
      v += __shfl_xor(v, 4);
      v += __shfl_xor(v, 8);
      if (li == 0) atomicAdd(&score[mrow + r], v);
    }
  }
#undef TILE_STEP
#undef MFMA_Q
#undef RD_B
#undef RD_A2
#undef STAGE_B
#undef STAGE_A
}

// ---------------------------------------------------------------------------
// Kernel 3 (fallback, ws too small): fp32-staging GEMM (passing)
// ---------------------------------------------------------------------------
__global__ void __launch_bounds__(256, 2) k_gemm_f32(
    const float* __restrict__ A, const unsigned short* __restrict__ Wt,
    const float* __restrict__ dech, const float* __restrict__ w_attn,
    const int* __restrict__ enc_len, float* __restrict__ score)
{
  int linear = blockIdx.x;
  int xcd = linear & 7;
  int j   = linear >> 3;
  int rb  = xcd * 64 + (j >> 3);
  int nb  = j & 7;
  int bb  = rb >> 4;
  int len = enc_len[bb];
  if (((rb & 15) * 128) >= len) return;

  __shared__ __align__(16) unsigned short sA[128 * 40];
  __shared__ __align__(16) unsigned short sB[128 * 32];

  int tid  = threadIdx.x;
  int w    = tid >> 6, lane = tid & 63;
  int wm   = (w >> 1) * 64, wn = (w & 1) * 64;
  int li   = lane & 15, g = lane >> 4;

  const float*          Abase = A  + (size_t)rb * 128 * DIM;
  const unsigned short* Bbase = Wt + (size_t)nb * 128 * DIM;

  floatx4 acc[4][4] = {};

  for (int kb = 0; kb < 32; ++kb) {
    __syncthreads();
#pragma unroll
    for (int i = 0; i < 2; ++i) {
      int c  = (w * 2 + i) * 64 + lane;
      int n  = c >> 2;
      int kh = (c & 3) ^ ((n >> 1) & 3);
      async16(Bbase + (size_t)n * DIM + kb * 32 + kh * 8, (char*)sB + (w * 2 + i) * 1024);
    }
#pragma unroll
    for (int i = 0; i < 4; ++i) {
      int f4  = tid + i * 256;
      int row = f4 >> 3, kq = f4 & 7;
      float4 v = *(const float4*)(Abase + (size_t)row * DIM + kb * 32 + kq * 4);
      ushort4 h;
      h.x = f2bf(v.x); h.y = f2bf(v.y); h.z = f2bf(v.z); h.w = f2bf(v.w);
      *(ushort4*)&sA[row * 40 + kq * 4] = h;
    }
    __syncthreads();

    short8 af[4], bfr[4];
#pragma unroll
    for (int t = 0; t < 4; ++t) {
      int row = wm + t * 16 + li;
      af[t] = *(const short8*)&sA[row * 40 + g * 8];
      int nl = wn + t * 16 + li;
      int phys = (nl << 2) | (g ^ ((nl >> 1) & 3));
      bfr[t] = *(const short8*)((const char*)sB + phys * 16);
    }
#pragma unroll
    for (int tm = 0; tm < 4; ++tm)
#pragma unroll
      for (int tn = 0; tn < 4; ++tn)
        acc[tm][tn] = __builtin_amdgcn_mfma_f32_16x16x32_bf16(af[tm], bfr[tn], acc[tm][tn], 0, 0, 0);
  }

  float dh[4], wa[4];
#pragma unroll
  for (int tn = 0; tn < 4; ++tn) {
    int n = nb * 128 + wn + tn * 16 + li;
    dh[tn] = dech[(size_t)bb * DIM + n];
    wa[tn] = w_attn[n];
  }
#pragma unroll
  for (int tm = 0; tm < 4; ++tm) {
    int mrow = rb * 128 + wm + tm * 16 + g * 4;
#pragma unroll
    for (int r = 0; r < 4; ++r) {
      float v = 0.0f;
#pragma unroll
      for (int tn = 0; tn < 4; ++tn)
        v = fmaf(wa[tn], fast_tanh(acc[tm][tn][r] + dh[tn]), v);
      v += __shfl_xor(v, 1);
      v += __shfl_xor(v, 2);
      v += __shfl_xor(v, 4);
      v += __shfl_xor(v, 8);
      if (li == 0) atomicAdd(&score[mrow + r], v);
    }
  }
}

// ---------------------------------------------------------------------------
// Kernel 4: masked softmax per batch row. SCALING == 1.0 (folded out).
// ---------------------------------------------------------------------------
__global__ void k_softmax(const float* __restrict__ score, const int* __restrict__ enc_len,
                          float* __restrict__ attn) {
  int b = blockIdx.x, tid = threadIdx.x;
  int len = enc_len[b];
  __shared__ float red[256];
  float v[8];
  float m = -1e30f;
#pragma unroll
  for (int i = 0; i < 8; ++i) {
    int s = tid + i * 256;
    v[i] = score[(size_t)b * SEQ + s];
    if (s < len) m = fmaxf(m, v[i]);
  }
  red[tid] = m; __syncthreads();
  for (int st = 128; st > 0; st >>= 1) {
    if (tid < st) red[tid] = fmaxf(red[tid], red[tid + st]);
    __syncthreads();
  }
  float mx = red[0]; __syncthreads();
  float sum = 0.0f;
#pragma unroll
  for (int i = 0; i < 8; ++i) {
    int s = tid + i * 256;
    float e = (s < len) ? __expf(v[i] - mx) : 0.0f;
    v[i] = e; sum += e;
  }
  red[tid] = sum; __syncthreads();
  for (int st = 128; st > 0; st >>= 1) {
    if (tid < st) red[tid] += red[tid + st];
    __syncthreads();
  }
  float inv = 1.0f / red[0];
#pragma unroll
  for (int i = 0; i < 8; ++i)
    attn[(size_t)b * SEQ + tid + i * 256] = v[i] * inv;
}

// ---------------------------------------------------------------------------
// Kernel 5: ctx[b][e] += sum_s attn[b][s] * enc[b][s][e]   (memory-bound)
// 32-row chunks, manual 8x unroll (8 float4 + 8 scalar loads in flight).
// ---------------------------------------------------------------------------
__global__ void k_context(const float* __restrict__ enc, const float* __restrict__ attn,
                          const int* __restrict__ enc_len, float* __restrict__ ctx) {
  int b = blockIdx.y, sc = blockIdx.x;   // 64 chunks of 32 rows
  int len = enc_len[b];
  int s0 = sc * 32;
  if (s0 >= len) return;
  int cnt = min(32, len - s0);
  int tid = threadIdx.x;
  const float* base = enc + ((size_t)b * SEQ + s0) * DIM + tid * 4;
  const float* ap   = attn + (size_t)b * SEQ + s0;
  float a0 = 0.f, a1 = 0.f, a2 = 0.f, a3 = 0.f;
  int i = 0;
  for (; i + 8 <= cnt; i += 8) {
    float4 x[8];
    float  w[8];
#pragma unroll
    for (int u = 0; u < 8; ++u)
      x[u] = *(const float4*)(base + (size_t)(i + u) * DIM);
#pragma unroll
    for (int u = 0; u < 8; ++u)
      w[u] = ap[i + u];
#pragma unroll
    for (int u = 0; u < 8; ++u) {
      a0 = fmaf(w[u], x[u].x, a0); a1 = fmaf(w[u], x[u].y, a1);
      a2 = fmaf(w[u], x[u].z, a2); a3 = fmaf(w[u], x[u].w, a3);
    }
  }
  for (; i < cnt; ++i) {
    float w = ap[i];
    float4 x = *(const float4*)(base + (size_t)i * DIM);
    a0 = fmaf(w, x.x, a0); a1 = fmaf(w, x.y, a1);
    a2 = fmaf(w, x.z, a2); a3 = fmaf(w, x.w, a3);
  }
  float* c = ctx + (size_t)b * DIM + tid * 4;
  atomicAdd(c + 0, a0); atomicAdd(c + 1, a1);
  atomicAdd(c + 2, a2); atomicAdd(c + 3, a3);
}

// ---------------------------------------------------------------------------
// Kernel 6: out[b][o] += ctx[b, z-chunk] @ W_out[z-chunk, o]
// R5: 8 batches per block (grid 4 x 4 x 8) so W_out is read 4x, not 32x.
// ---------------------------------------------------------------------------
__global__ void k_out(const float* __restrict__ ctx, const float* __restrict__ W_out,
                      const float* __restrict__ b_out, float* __restrict__ out) {
  int o  = blockIdx.x * 256 + threadIdx.x;
  int bg = blockIdx.y * 8;
  int z  = blockIdx.z;
  float bias = (z == 0) ? b_out[o] : 0.0f;
  float acc[8];
#pragma unroll
  for (int j = 0; j < 8; ++j) acc[j] = bias;
  const float* wc = W_out + (size_t)z * 128 * DIM + o;
#pragma unroll 4
  for (int e = 0; e < 128; ++e) {
    float w = wc[(size_t)e * DIM];
#pragma unroll
    for (int j = 0; j < 8; ++j)
      acc[j] = fmaf(ctx[(size_t)(bg + j) * DIM + z * 128 + e], w, acc[j]);
  }
#pragma unroll
  for (int j = 0; j < 8; ++j)
    atomicAdd(&out[(size_t)(bg + j) * DIM + o], acc[j]);
}

// ---------------------------------------------------------------------------
extern "C" void kernel_launch(void* const* d_in, const int* in_sizes, int n_in,
                              void* d_out, int out_size, void* d_ws, size_t ws_size,
                              hipStream_t stream) {
  (void)in_sizes; (void)n_in; (void)out_size;
  const float* enc_states = (const float*)d_in[0];   // [32,2048,1024]
  const float* dec_states = (const float*)d_in[1];   // [32,1024]
  const float* W_enc      = (const float*)d_in[2];   // [1024,1024]
  const float* b_enc      = (const float*)d_in[3];   // [1024]
  const float* W_dec      = (const float*)d_in[4];   // [1024,1024]
  const float* b_dec      = (const float*)d_in[5];   // [1024]
  const float* w_attn     = (const float*)d_in[6];   // [1024]
  const float* W_out      = (const float*)d_in[7];   // [1024,1024]
  const float* b_out      = (const float*)d_in[8];   // [1024]
  const int*   enc_len    = (const int*)  d_in[9];   // [32]

  float* out_ctx  = (float*)d_out;                   // [32,1024]
  float* out_attn = (float*)d_out + BATCH * DIM;     // [32,2048]

  // workspace layout:
  //   Wt    @ 0        : 2 MB   (bf16 W_enc^T)
  //   score @ 2 MB     : 256 KB (zeroed)
  //   ctx   @ 2.25 MB  : 128 KB (zeroed)
  //   dech  @ 2.375 MB : 128 KB (zeroed)
  //   Abf   @ 3 MB     : 128 MB (bf16 enc_states) -- fast path only
  char* ws = (char*)d_ws;
  unsigned short* Wt  = (unsigned short*)ws;
  float* score = (float*)(ws + (2u << 20));
  float* ctx   = (float*)(ws + (2u << 20) + 262144);
  float* dech  = (float*)(ws + (2u << 20) + 262144 + 131072);
  unsigned short* Abf = (unsigned short*)(ws + (3u << 20));
  const bool fast = ws_size >= ((size_t)(3u << 20) + ((size_t)MROWS * DIM * 2));

  // zero score + ctx + dech (all atomically accumulated)
  hipMemsetAsync(ws + (2u << 20), 0, 262144 + 131072 + 131072, stream);
  // zero out_ctx (atomically accumulated by k_out)
  hipMemsetAsync(d_out, 0, (size_t)BATCH * DIM * sizeof(float), stream);

  k_transpose<<<dim3(32, 32), dim3(32, 8), 0, stream>>>(W_enc, Wt);
  k_dech<<<dim3(4, 4, 8), 256, 0, stream>>>(dec_states, W_dec, b_dec, b_enc, dech);
  if (fast) {
    k_convert<<<dim3(SEQ / 8, BATCH), 256, 0, stream>>>(enc_states, enc_len, Abf);
    k_gemm256<<<1024, 512, 0, stream>>>(Abf, Wt, dech, w_attn, enc_len, score);
  } else {
    k_gemm_f32<<<4096, 256, 0, stream>>>(enc_states, Wt, dech, w_attn, enc_len, score);
  }
  k_softmax<<<BATCH, 256, 0, stream>>>(score, enc_len, out_attn);
  k_context<<<dim3(64, BATCH), 256, 0, stream>>>(enc_states, out_attn, enc_len, ctx);
  k_out<<<dim3(4, 4, 8), 256, 0, stream>>>(ctx, W_out, b_out, out_ctx);
}

// Round 6
// 583.561 us; speedup vs baseline: 1.0485x; 1.0485x over previous
//
#include <hip/hip_runtime.h>
#include <cstdint>
#include <cstddef>

// Problem constants (fixed by reference)
#define BATCH 32
#define SEQ   2048
#define DIM   1024      // ENC_D = DEC_D = ATTN_D = OUT_D = 1024
#define MROWS (BATCH*SEQ)   // 65536

typedef __attribute__((ext_vector_type(4))) float  floatx4;
typedef __attribute__((ext_vector_type(8))) short  short8;

// fp32 -> bf16 round-to-nearest-even
__device__ __forceinline__ unsigned short f2bf(float f) {
  unsigned int u = __float_as_uint(f);
  u += 0x7fffu + ((u >> 16) & 1u);
  return (unsigned short)(u >> 16);
}

// async global->LDS, 16B per lane; LDS dest = wave-uniform base + lane*16
__device__ __forceinline__ void async16(const void* g, void* l) {
  __builtin_amdgcn_global_load_lds(
      (const __attribute__((address_space(1))) unsigned int*)g,
      (__attribute__((address_space(3))) unsigned int*)l, 16, 0, 0);
}

__device__ __forceinline__ float fast_tanh(float x) {
  float e = __expf(2.0f * x);
  return 1.0f - 2.0f * __builtin_amdgcn_rcpf(1.0f + e);
}

// ---------------------------------------------------------------------------
// Kernel P (fast path): fused prep = transpose + dech + convert in ONE launch.
// Independent jobs partitioned by blockIdx.x; small jobs FIRST so they
// overlap under convert's duration (saves 2 launch gaps + tails).
//   [0,1024)    : Wt[n][k] = bf16(W_enc[k][n])
//   [1024,1152) : dech[b][a] += dec[b]z @ W_dec z  (8 batches/block, splitK x8)
//   [1152,9344) : Abf = bf16(enc_states), rows >= len skipped
// ---------------------------------------------------------------------------
__global__ void k_prep(const float* __restrict__ enc, const int* __restrict__ enc_len,
                       unsigned short* __restrict__ Abf,
                       const float* __restrict__ W_enc, unsigned short* __restrict__ Wt,
                       const float* __restrict__ dec, const float* __restrict__ W_dec,
                       const float* __restrict__ b_dec, const float* __restrict__ b_enc,
                       float* __restrict__ dech) {
  __shared__ float tile[32][33];
  int blk = blockIdx.x;
  int tid = threadIdx.x;
  if (blk < 1024) {
    // ---- transpose W_enc -> Wt (32x32 tiles) ----
    int n0 = (blk & 31) * 32, k0 = (blk >> 5) * 32;
    int tx = tid & 31, ty = tid >> 5;   // (32, 8)
#pragma unroll
    for (int i = 0; i < 4; ++i) {
      int y = ty + i * 8;
      tile[y][tx] = W_enc[(size_t)(k0 + y) * DIM + n0 + tx];
    }
    __syncthreads();
#pragma unroll
    for (int i = 0; i < 4; ++i) {
      int y = ty + i * 8;
      Wt[(size_t)(n0 + y) * DIM + k0 + tx] = f2bf(tile[tx][y]);
    }
  } else if (blk < 1152) {
    // ---- dech: 8 batches/block, split-K x8; z==0 adds biases ----
    int db = blk - 1024;
    int ax = db & 3, bgi = (db >> 2) & 3, z = db >> 4;
    int a  = ax * 256 + tid;
    int bg = bgi * 8;
    float bias = (z == 0) ? (b_dec[a] + b_enc[a]) : 0.0f;
    float acc[8];
#pragma unroll
    for (int j = 0; j < 8; ++j) acc[j] = bias;
    const float* wcp = W_dec + (size_t)z * 128 * DIM + a;
#pragma unroll 4
    for (int e = 0; e < 128; ++e) {
      float w = wcp[(size_t)e * DIM];
#pragma unroll
      for (int j = 0; j < 8; ++j)
        acc[j] = fmaf(dec[(size_t)(bg + j) * DIM + z * 128 + e], w, acc[j]);
    }
#pragma unroll
    for (int j = 0; j < 8; ++j)
      atomicAdd(&dech[(size_t)(bg + j) * DIM + a], acc[j]);
  } else {
    // ---- convert: Abf = bf16(enc), 8 rows/block, skip masked row-chunks ----
    int cv = blk - 1152;
    int b = cv >> 8, rc = cv & 255;
    int r0 = rc * 8;
    if (r0 >= enc_len[b]) return;
    size_t base = ((size_t)b * SEQ + r0) * DIM;
    const float4* src = (const float4*)(enc + base);
    ushort4* dst = (ushort4*)(Abf + base);
#pragma unroll
    for (int i = 0; i < 8; ++i) {
      float4 v = src[tid + i * 256];
      ushort4 h;
      h.x = f2bf(v.x); h.y = f2bf(v.y); h.z = f2bf(v.z); h.w = f2bf(v.w);
      dst[tid + i * 256] = h;
    }
  }
}

// ---------------------------------------------------------------------------
// Kernel 1 (fallback path only): Wt[n][k] = bf16(W_enc[k][n])
// ---------------------------------------------------------------------------
__global__ void k_transpose(const float* __restrict__ W, unsigned short* __restrict__ Wt) {
  __shared__ float tile[32][33];
  int n0 = blockIdx.x * 32, k0 = blockIdx.y * 32;
  int tx = threadIdx.x, ty = threadIdx.y;   // (32, 8)
#pragma unroll
  for (int i = 0; i < 4; ++i) {
    int y = ty + i * 8;
    tile[y][tx] = W[(size_t)(k0 + y) * DIM + n0 + tx];
  }
  __syncthreads();
#pragma unroll
  for (int i = 0; i < 4; ++i) {
    int y = ty + i * 8;
    Wt[(size_t)(n0 + y) * DIM + k0 + tx] = f2bf(tile[tx][y]);
  }
}

// ---------------------------------------------------------------------------
// Kernel 2 (fallback path only): dech, 8 batches/block
// ---------------------------------------------------------------------------
__global__ void k_dech(const float* __restrict__ dec, const float* __restrict__ W_dec,
                       const float* __restrict__ b_dec, const float* __restrict__ b_enc,
                       float* __restrict__ dech) {
  int a  = blockIdx.x * 256 + threadIdx.x;
  int bg = blockIdx.y * 8;
  int z  = blockIdx.z;
  float bias = (z == 0) ? (b_dec[a] + b_enc[a]) : 0.0f;
  float acc[8];
#pragma unroll
  for (int j = 0; j < 8; ++j) acc[j] = bias;
  const float* wc = W_dec + (size_t)z * 128 * DIM + a;
#pragma unroll 4
  for (int e = 0; e < 128; ++e) {
    float w = wc[(size_t)e * DIM];
#pragma unroll
    for (int j = 0; j < 8; ++j)
      acc[j] = fmaf(dec[(size_t)(bg + j) * DIM + z * 128 + e], w, acc[j]);
  }
#pragma unroll
  for (int j = 0; j < 8; ++j)
    atomicAdd(&dech[(size_t)(bg + j) * DIM + a], acc[j]);
}

// ---------------------------------------------------------------------------
// Kernel 3: 256x256-tile 8-phase GEMM + tanh-dot epilogue.
//   score[m] += sum_n tanh( (Abf@Wt^T)[m][n] + dech[b(m)][n] ) * w_attn[n]
// R6: SPLIT into two 512-block dispatches (nbase = 0 / 2) for profiler
// visibility -- schedule code identical to R5, only bid->(rt,nb) mapping
// changed (bijective per half: t=(bid&7)*64+(bid>>3), 512%8==0).
// BM=BN=256, BK=64, 512 thr = 8 waves (2M x 4N), per-wave 128x64 out.
// LDS 128 KB; swizzle physical = logical ^ (((logical>>7)&7)<<4).
// R5 schedule: {8,4,8,4} reads, full-tile-deep prefetch, VMCNT(8)/tile.
// ---------------------------------------------------------------------------
#define PH_BAR do { asm volatile("" ::: "memory"); __builtin_amdgcn_s_barrier(); asm volatile("" ::: "memory"); } while(0)
#define SCHED0 __builtin_amdgcn_sched_barrier(0)
#define SP1 __builtin_amdgcn_s_setprio(1)
#define SP0 __builtin_amdgcn_s_setprio(0)
#define VMCNT(n) asm volatile("s_waitcnt vmcnt(" #n ")" ::: "memory")

__global__ void __launch_bounds__(512, 2) k_gemm256(
    const unsigned short* __restrict__ Abf, // [65536,1024] bf16
    const unsigned short* __restrict__ Wt,  // [1024 n][1024 k] bf16
    const float* __restrict__ dech,         // [32,1024]
    const float* __restrict__ w_attn,       // [1024]
    const int* __restrict__ enc_len,        // [32]
    float* __restrict__ score,              // [65536], pre-zeroed
    int nbase)                              // 0 or 2 (n-half)
{
  int bid = blockIdx.x;                 // 0..511
  int t  = (bid & 7) * 64 + (bid >> 3); // bijective XCD swizzle (512%8==0)
  int nb = nbase + (t & 1);             // col tile (n0 = nb*256)
  int rt = t >> 1;                      // row tile 0..255 (m0 = rt*256)
  int bb = rt >> 3;                     // batch (8 row-tiles per batch)
  int len = enc_len[bb];
  if (((rt & 7) * 256) >= len) return;  // fully masked tile

  __shared__ __align__(16) char lds[131072];

  int tid = threadIdx.x;
  int w = tid >> 6, lane = tid & 63;
  int wr = w >> 2;               // 0..1  M-warp
  int wc = w & 3;                // 0..3  N-warp
  int li = lane & 15, g = lane >> 4;
  int xl = (li & 7) << 4;        // lane-constant read swizzle

  const char* Ag = (const char*)(Abf + (size_t)rt * 256 * DIM);
  const char* Bg = (const char*)(Wt  + (size_t)nb * 256 * DIM);

  // pre-swizzled stage source offsets, collapsed to linear form
  size_t sbase = (size_t)((lane >> 3) * 2048 +
                 (((lane & 7) << 4) ^ (((lane >> 3) & 7) << 4)));
  size_t swoff = (size_t)(w * 2) * 16384;   // i adds 16384; h adds 262144
  int    ldbase = w * 2048;                 // wave-uniform LDS dest

#define STAGE_A(buf, h, kt) do { \
  async16(Ag + sbase + swoff + (size_t)(h) * 262144 + (size_t)(kt) * 128, \
          lds + (buf) * 32768 + ldbase + (h) * 16384); \
  async16(Ag + sbase + swoff + 16384 + (size_t)(h) * 262144 + (size_t)(kt) * 128, \
          lds + (buf) * 32768 + ldbase + 1024 + (h) * 16384); \
} while (0)
#define STAGE_B(buf, h, kt) do { \
  async16(Bg + sbase + swoff + (size_t)(h) * 262144 + (size_t)(kt) * 128, \
          lds + 65536 + (buf) * 32768 + ldbase + (h) * 16384); \
  async16(Bg + sbase + swoff + 16384 + (size_t)(h) * 262144 + (size_t)(kt) * 128, \
          lds + 65536 + (buf) * 32768 + ldbase + 1024 + (h) * 16384); \
} while (0)

  short8 sA0[2][2], sA1[2][2];   // rotating A f01 / B1 slots
  short8 aX[2][2];               // A high frag-pair of current half
  short8 bX[2][2];               // B0
  floatx4 acc[8][4] = {};        // 8 m-frags x 4 n-frags

#define RD_A2(buf, f0, DST) do { \
  const char* base_ = lds + (buf) * 32768 + (wr * 128 + (f0) * 16 + li) * 128; \
  int c0_ = (g * 16) ^ xl; \
  _Pragma("unroll") for (int j = 0; j < 2; ++j) { \
    DST[j][0] = *(const short8*)(base_ + j * 2048 + c0_); \
    DST[j][1] = *(const short8*)(base_ + j * 2048 + (c0_ ^ 64)); \
  } \
} while (0)
#define RD_B(buf, nh, DST) do { \
  const char* base_ = lds + 65536 + (buf) * 32768 + (wc * 64 + (nh) * 32 + li) * 128; \
  int c0_ = (g * 16) ^ xl; \
  _Pragma("unroll") for (int tnq = 0; tnq < 2; ++tnq) { \
    DST[tnq][0] = *(const short8*)(base_ + tnq * 2048 + c0_); \
    DST[tnq][1] = *(const short8*)(base_ + tnq * 2048 + (c0_ ^ 64)); \
  } \
} while (0)
#define MFMA_Q(mh, nh, ALO, AHI, BB) do { \
  _Pragma("unroll") for (int ks = 0; ks < 2; ++ks) \
  _Pragma("unroll") for (int tnq = 0; tnq < 2; ++tnq) { \
    acc[(mh)*4+0][(nh)*2+tnq] = __builtin_amdgcn_mfma_f32_16x16x32_bf16(ALO[0][ks], BB[tnq][ks], acc[(mh)*4+0][(nh)*2+tnq], 0, 0, 0); \
    acc[(mh)*4+1][(nh)*2+tnq] = __builtin_amdgcn_mfma_f32_16x16x32_bf16(ALO[1][ks], BB[tnq][ks], acc[(mh)*4+1][(nh)*2+tnq], 0, 0, 0); \
    acc[(mh)*4+2][(nh)*2+tnq] = __builtin_amdgcn_mfma_f32_16x16x32_bf16(AHI[0][ks], BB[tnq][ks], acc[(mh)*4+2][(nh)*2+tnq], 0, 0, 0); \
    acc[(mh)*4+3][(nh)*2+tnq] = __builtin_amdgcn_mfma_f32_16x16x32_bf16(AHI[1][ks], BB[tnq][ks], acc[(mh)*4+3][(nh)*2+tnq], 0, 0, 0); \
  } \
} while (0)

#define TILE_STEP(CUR, KT2, MODE, SP_, SQ_) do { \
  RD_A2(CUR, 2, aX); \
  RD_B(CUR, 0, bX); \
  PH_BAR; SCHED0; SP1; MFMA_Q(0, 0, SP_, aX, bX); SP0; SCHED0; \
  PH_BAR; \
  RD_B(CUR, 1, SQ_); \
  PH_BAR; SCHED0; SP1; MFMA_Q(0, 1, SP_, aX, SQ_); SP0; SCHED0; \
  PH_BAR; \
  if ((MODE) == 0) { STAGE_B(CUR, 0, KT2); STAGE_B(CUR, 1, KT2); } \
  RD_A2(CUR, 4, SP_); \
  RD_A2(CUR, 6, aX); \
  PH_BAR; SCHED0; SP1; MFMA_Q(1, 1, SP_, aX, SQ_); SP0; SCHED0; \
  PH_BAR; \
  if ((MODE) == 0) { STAGE_A(CUR, 0, KT2); STAGE_A(CUR, 1, KT2); } \
  if ((MODE) == 0) { VMCNT(8); } else if ((MODE) == 1) { VMCNT(0); } \
  if ((MODE) < 2) RD_A2((CUR) ^ 1, 0, SQ_); \
  PH_BAR; SCHED0; SP1; MFMA_Q(1, 0, SP_, aX, bX); SP0; SCHED0; \
  PH_BAR; \
} while (0)

  // prologue: L(0)->buf0, L(1)->buf1; VMCNT(8) retires L(0)
  STAGE_B(0, 0, 0); STAGE_B(0, 1, 0); STAGE_A(0, 0, 0); STAGE_A(0, 1, 0);
  STAGE_B(1, 0, 1); STAGE_B(1, 1, 1); STAGE_A(1, 0, 1); STAGE_A(1, 1, 1);
  VMCNT(8);
  PH_BAR;
  RD_A2(0, 0, sA0);   // tile0 f01

  // main: tiles 0..13 stage tiles 2..15 (NT=16)
#pragma unroll 1
  for (int u = 0; u < 14; u += 2) {
    TILE_STEP(0, u + 2, 0, sA0, sA1);
    TILE_STEP(1, u + 3, 0, sA1, sA0);
  }
  TILE_STEP(0, 0, 1, sA0, sA1);   // tile 14
  TILE_STEP(1, 0, 2, sA1, sA0);   // tile 15

  // epilogue: C/D layout col=lane&15 (n), row=(lane>>4)*4+reg (m)  [m89]
  float dh[4], wa[4];
#pragma unroll
  for (int tn = 0; tn < 4; ++tn) {
    int n = nb * 256 + wc * 64 + tn * 16 + li;
    dh[tn] = dech[(size_t)bb * DIM + n];
    wa[tn] = w_attn[n];
  }
#pragma unroll
  for (int tm = 0; tm < 8; ++tm) {
    int mrow = rt * 256 + wr * 128 + tm * 16 + g * 4;
#pragma unroll
    for (int r = 0; r < 4; ++r) {
      float v = 0.0f;
#pragma unroll
      for (int tn = 0; tn < 4; ++tn)
        v = fmaf(wa[tn], fast_tanh(acc[tm][tn][r] + dh[tn]), v);
      v += __shfl_xor(v, 1);
      v += __shfl_xor(v, 2);
      v += __shfl_xor(v, 4);
      v += __shfl_xor(v, 8);
      if (li == 0) atomicAdd(&score[mrow + r], v);
    }
  }
#undef TILE_STEP
#undef MFMA_Q
#undef RD_B
#undef RD_A2
#undef STAGE_B
#undef STAGE_A
}

// ---------------------------------------------------------------------------
// Kernel 3 (fallback, ws too small): fp32-staging GEMM (passing)
// ---------------------------------------------------------------------------
__global__ void __launch_bounds__(256, 2) k_gemm_f32(
    const float* __restrict__ A, const unsigned short* __restrict__ Wt,
    const float* __restrict__ dech, const float* __restrict__ w_attn,
    const int* __restrict__ enc_len, float* __restrict__ score)
{
  int linear = blockIdx.x;
  int xcd = linear & 7;
  int j   = linear >> 3;
  int rb  = xcd * 64 + (j >> 3);
  int nb  = j & 7;
  int bb  = rb >> 4;
  int len = enc_len[bb];
  if (((rb & 15) * 128) >= len) return;

  __shared__ __align__(16) unsigned short sA[128 * 40];
  __shared__ __align__(16) unsigned short sB[128 * 32];

  int tid  = threadIdx.x;
  int w    = tid >> 6, lane = tid & 63;
  int wm   = (w >> 1) * 64, wn = (w & 1) * 64;
  int li   = lane & 15, g = lane >> 4;

  const float*          Abase = A  + (size_t)rb * 128 * DIM;
  const unsigned short* Bbase = Wt + (size_t)nb * 128 * DIM;

  floatx4 acc[4][4] = {};

  for (int kb = 0; kb < 32; ++kb) {
    __syncthreads();
#pragma unroll
    for (int i = 0; i < 2; ++i) {
      int c  = (w * 2 + i) * 64 + lane;
      int n  = c >> 2;
      int kh = (c & 3) ^ ((n >> 1) & 3);
      async16(Bbase + (size_t)n * DIM + kb * 32 + kh * 8, (char*)sB + (w * 2 + i) * 1024);
    }
#pragma unroll
    for (int i = 0; i < 4; ++i) {
      int f4  = tid + i * 256;
      int row = f4 >> 3, kq = f4 & 7;
      float4 v = *(const float4*)(Abase + (size_t)row * DIM + kb * 32 + kq * 4);
      ushort4 h;
      h.x = f2bf(v.x); h.y = f2bf(v.y); h.z = f2bf(v.z); h.w = f2bf(v.w);
      *(ushort4*)&sA[row * 40 + kq * 4] = h;
    }
    __syncthreads();

    short8 af[4], bfr[4];
#pragma unroll
    for (int t = 0; t < 4; ++t) {
      int row = wm + t * 16 + li;
      af[t] = *(const short8*)&sA[row * 40 + g * 8];
      int nl = wn + t * 16 + li;
      int phys = (nl << 2) | (g ^ ((nl >> 1) & 3));
      bfr[t] = *(const short8*)((const char*)sB + phys * 16);
    }
#pragma unroll
    for (int tm = 0; tm < 4; ++tm)
#pragma unroll
      for (int tn = 0; tn < 4; ++tn)
        acc[tm][tn] = __builtin_amdgcn_mfma_f32_16x16x32_bf16(af[tm], bfr[tn], acc[tm][tn], 0, 0, 0);
  }

  float dh[4], wa[4];
#pragma unroll
  for (int tn = 0; tn < 4; ++tn) {
    int n = nb * 128 + wn + tn * 16 + li;
    dh[tn] = dech[(size_t)bb * DIM + n];
    wa[tn] = w_attn[n];
  }
#pragma unroll
  for (int tm = 0; tm < 4; ++tm) {
    int mrow = rb * 128 + wm + tm * 16 + g * 4;
#pragma unroll
    for (int r = 0; r < 4; ++r) {
      float v = 0.0f;
#pragma unroll
      for (int tn = 0; tn < 4; ++tn)
        v = fmaf(wa[tn], fast_tanh(acc[tm][tn][r] + dh[tn]), v);
      v += __shfl_xor(v, 1);
      v += __shfl_xor(v, 2);
      v += __shfl_xor(v, 4);
      v += __shfl_xor(v, 8);
      if (li == 0) atomicAdd(&score[mrow + r], v);
    }
  }
}

// ---------------------------------------------------------------------------
// Kernel 4: masked softmax per batch row. SCALING == 1.0 (folded out).
// ---------------------------------------------------------------------------
__global__ void k_softmax(const float* __restrict__ score, const int* __restrict__ enc_len,
                          float* __restrict__ attn) {
  int b = blockIdx.x, tid = threadIdx.x;
  int len = enc_len[b];
  __shared__ float red[256];
  float v[8];
  float m = -1e30f;
#pragma unroll
  for (int i = 0; i < 8; ++i) {
    int s = tid + i * 256;
    v[i] = score[(size_t)b * SEQ + s];
    if (s < len) m = fmaxf(m, v[i]);
  }
  red[tid] = m; __syncthreads();
  for (int st = 128; st > 0; st >>= 1) {
    if (tid < st) red[tid] = fmaxf(red[tid], red[tid + st]);
    __syncthreads();
  }
  float mx = red[0]; __syncthreads();
  float sum = 0.0f;
#pragma unroll
  for (int i = 0; i < 8; ++i) {
    int s = tid + i * 256;
    float e = (s < len) ? __expf(v[i] - mx) : 0.0f;
    v[i] = e; sum += e;
  }
  red[tid] = sum; __syncthreads();
  for (int st = 128; st > 0; st >>= 1) {
    if (tid < st) red[tid] += red[tid + st];
    __syncthreads();
  }
  float inv = 1.0f / red[0];
#pragma unroll
  for (int i = 0; i < 8; ++i)
    attn[(size_t)b * SEQ + tid + i * 256] = v[i] * inv;
}

// ---------------------------------------------------------------------------
// Kernel 5: ctx[b][e] += sum_s attn[b][s] * enc[b][s][e]   (memory-bound)
// 32-row chunks, manual 8x unroll (8 float4 + 8 scalar loads in flight).
// ---------------------------------------------------------------------------
__global__ void k_context(const float* __restrict__ enc, const float* __restrict__ attn,
                          const int* __restrict__ enc_len, float* __restrict__ ctx) {
  int b = blockIdx.y, sc = blockIdx.x;   // 64 chunks of 32 rows
  int len = enc_len[b];
  int s0 = sc * 32;
  if (s0 >= len) return;
  int cnt = min(32, len - s0);
  int tid = threadIdx.x;
  const float* base = enc + ((size_t)b * SEQ + s0) * DIM + tid * 4;
  const float* ap   = attn + (size_t)b * SEQ + s0;
  float a0 = 0.f, a1 = 0.f, a2 = 0.f, a3 = 0.f;
  int i = 0;
  for (; i + 8 <= cnt; i += 8) {
    float4 x[8];
    float  w[8];
#pragma unroll
    for (int u = 0; u < 8; ++u)
      x[u] = *(const float4*)(base + (size_t)(i + u) * DIM);
#pragma unroll
    for (int u = 0; u < 8; ++u)
      w[u] = ap[i + u];
#pragma unroll
    for (int u = 0; u < 8; ++u) {
      a0 = fmaf(w[u], x[u].x, a0); a1 = fmaf(w[u], x[u].y, a1);
      a2 = fmaf(w[u], x[u].z, a2); a3 = fmaf(w[u], x[u].w, a3);
    }
  }
  for (; i < cnt; ++i) {
    float w = ap[i];
    float4 x = *(const float4*)(base + (size_t)i * DIM);
    a0 = fmaf(w, x.x, a0); a1 = fmaf(w, x.y, a1);
    a2 = fmaf(w, x.z, a2); a3 = fmaf(w, x.w, a3);
  }
  float* c = ctx + (size_t)b * DIM + tid * 4;
  atomicAdd(c + 0, a0); atomicAdd(c + 1, a1);
  atomicAdd(c + 2, a2); atomicAdd(c + 3, a3);
}

// ---------------------------------------------------------------------------
// Kernel 6: out[b][o] += ctx[b, z-chunk] @ W_out[z-chunk, o]
// 8 batches/block (grid 4 x 4 x 8) so W_out is read 4x, not 32x.
// ---------------------------------------------------------------------------
__global__ void k_out(const float* __restrict__ ctx, const float* __restrict__ W_out,
                      const float* __restrict__ b_out, float* __restrict__ out) {
  int o  = blockIdx.x * 256 + threadIdx.x;
  int bg = blockIdx.y * 8;
  int z  = blockIdx.z;
  float bias = (z == 0) ? b_out[o] : 0.0f;
  float acc[8];
#pragma unroll
  for (int j = 0; j < 8; ++j) acc[j] = bias;
  const float* wc = W_out + (size_t)z * 128 * DIM + o;
#pragma unroll 4
  for (int e = 0; e < 128; ++e) {
    float w = wc[(size_t)e * DIM];
#pragma unroll
    for (int j = 0; j < 8; ++j)
      acc[j] = fmaf(ctx[(size_t)(bg + j) * DIM + z * 128 + e], w, acc[j]);
  }
#pragma unroll
  for (int j = 0; j < 8; ++j)
    atomicAdd(&out[(size_t)(bg + j) * DIM + o], acc[j]);
}

// ---------------------------------------------------------------------------
extern "C" void kernel_launch(void* const* d_in, const int* in_sizes, int n_in,
                              void* d_out, int out_size, void* d_ws, size_t ws_size,
                              hipStream_t stream) {
  (void)in_sizes; (void)n_in; (void)out_size;
  const float* enc_states = (const float*)d_in[0];   // [32,2048,1024]
  const float* dec_states = (const float*)d_in[1];   // [32,1024]
  const float* W_enc      = (const float*)d_in[2];   // [1024,1024]
  const float* b_enc      = (const float*)d_in[3];   // [1024]
  const float* W_dec      = (const float*)d_in[4];   // [1024,1024]
  const float* b_dec      = (const float*)d_in[5];   // [1024]
  const float* w_attn     = (const float*)d_in[6];   // [1024]
  const float* W_out      = (const float*)d_in[7];   // [1024,1024]
  const float* b_out      = (const float*)d_in[8];   // [1024]
  const int*   enc_len    = (const int*)  d_in[9];   // [32]

  float* out_ctx  = (float*)d_out;                   // [32,1024]
  float* out_attn = (float*)d_out + BATCH * DIM;     // [32,2048]

  // workspace layout:
  //   Wt    @ 0        : 2 MB   (bf16 W_enc^T)
  //   score @ 2 MB     : 256 KB (zeroed)
  //   ctx   @ 2.25 MB  : 128 KB (zeroed)
  //   dech  @ 2.375 MB : 128 KB (zeroed)
  //   Abf   @ 3 MB     : 128 MB (bf16 enc_states) -- fast path only
  char* ws = (char*)d_ws;
  unsigned short* Wt  = (unsigned short*)ws;
  float* score = (float*)(ws + (2u << 20));
  float* ctx   = (float*)(ws + (2u << 20) + 262144);
  float* dech  = (float*)(ws + (2u << 20) + 262144 + 131072);
  unsigned short* Abf = (unsigned short*)(ws + (3u << 20));
  const bool fast = ws_size >= ((size_t)(3u << 20) + ((size_t)MROWS * DIM * 2));

  // zero score + ctx + dech (all atomically accumulated)
  hipMemsetAsync(ws + (2u << 20), 0, 262144 + 131072 + 131072, stream);
  // zero out_ctx (atomically accumulated by k_out)
  hipMemsetAsync(d_out, 0, (size_t)BATCH * DIM * sizeof(float), stream);

  if (fast) {
    k_prep<<<9344, 256, 0, stream>>>(enc_states, enc_len, Abf,
                                     W_enc, Wt, dec_states, W_dec, b_dec, b_enc, dech);
    k_gemm256<<<512, 512, 0, stream>>>(Abf, Wt, dech, w_attn, enc_len, score, 0);
    k_gemm256<<<512, 512, 0, stream>>>(Abf, Wt, dech, w_attn, enc_len, score, 2);
  } else {
    k_transpose<<<dim3(32, 32), dim3(32, 8), 0, stream>>>(W_enc, Wt);
    k_dech<<<dim3(4, 4, 8), 256, 0, stream>>>(dec_states, W_dec, b_dec, b_enc, dech);
    k_gemm_f32<<<4096, 256, 0, stream>>>(enc_states, Wt, dech, w_attn, enc_len, score);
  }
  k_softmax<<<BATCH, 256, 0, stream>>>(score, enc_len, out_attn);
  k_context<<<dim3(64, BATCH), 256, 0, stream>>>(enc_states, out_attn, enc_len, ctx);
  k_out<<<dim3(4, 4, 8), 256, 0, stream>>>(ctx, W_out, b_out, out_ctx);
}